// Round 15
// baseline (34.868 us; speedup 1.0000x reference)
//
#include <hip/hip_runtime.h>

typedef __attribute__((ext_vector_type(8))) short short8;
typedef __attribute__((ext_vector_type(4))) float f32x4;
typedef __attribute__((ext_vector_type(4))) unsigned int u32x4;

static __device__ inline unsigned short f2bf(float x) {
    unsigned int u = __float_as_uint(x);
    u = (u + 0x7FFFu + ((u >> 16) & 1u)) >> 16;
    return (unsigned short)u;
}

static __device__ inline unsigned int pk(float a, float b, float inv) {
    return (unsigned int)f2bf(a * inv) | ((unsigned int)f2bf(b * inv) << 16);
}

// ------------- Kernel 1: fused normalize + partial max_q dot via MFMA -------
// Single-barrier structure: stage the block's WHOLE 256-q B slice (normalized
// bf16, XOR-swizzled, 64 KB) into LDS once, ONE __syncthreads, then each wave
// free-runs 256 MFMAs off read-only LDS -- no per-phase barriers/vmcnt at all.
// (R14 post-mortem: normalize VALU inside the 16-barrier lockstep loop killed
// MfmaUtil to 7.4%; R11/m233: per-phase barrier drains were ~75% of time.)
// Inputs read from d_in (L2-cached; R14 confirmed); d_ws only sp_part (512KB).
// grid (8 m, 64 = ptile*4+qq), 256 thr = 4 waves; block = 256p x 256q;
// 2 blocks/CU (LDS 64KB, launch_bounds(256,2)).
__global__ __launch_bounds__(256, 2) void kscore(const float* __restrict__ feats,
                                                 const float* __restrict__ nfeats,
                                                 float* __restrict__ sp_part) {
    __shared__ char gtile[256 * 256];        // 64 KB bf16, swizzled image
    const int tid = threadIdx.x;
    const int lane = tid & 63;
    const int wave = tid >> 6;               // 0..3 = p-subtile
    const int l15 = lane & 15, lhi = lane >> 4;
    const int m = blockIdx.x;                // XCD-pinned nfeats slice
    const int ptile = blockIdx.y >> 2, qq = blockIdx.y & 3;
    const int rowbase = ptile * 256 + wave * 64;   // f row in [0,4096)

    const float* gBase = nfeats + ((size_t)m * 1024 + qq * 256) * 128;

    // ---- A fragments: 4 p-groups; normalize across the 4 lanes sharing l15 --
    short8 a[4][4];
    #pragma unroll
    for (int pg = 0; pg < 4; pg++) {
        const float* arow = feats + (size_t)(rowbase + pg * 16 + l15) * 128 + lhi * 8;
        f32x4 vx[4], vy[4];
        float ss = 0.f;
        #pragma unroll
        for (int kk = 0; kk < 4; kk++) {
            vx[kk] = *(const f32x4*)(arow + kk * 32);
            vy[kk] = *(const f32x4*)(arow + kk * 32 + 4);
            #pragma unroll
            for (int j = 0; j < 4; j++) ss += vx[kk][j]*vx[kk][j] + vy[kk][j]*vy[kk][j];
        }
        ss += __shfl_xor(ss, 16);
        ss += __shfl_xor(ss, 32);
        float inv = 1.0f / sqrtf(ss);
        #pragma unroll
        for (int kk = 0; kk < 4; kk++) {
            u32x4 o;
            o.x = pk(vx[kk][0], vx[kk][1], inv);
            o.y = pk(vx[kk][2], vx[kk][3], inv);
            o.z = pk(vy[kk][0], vy[kk][1], inv);
            o.w = pk(vy[kk][2], vy[kk][3], inv);
            a[pg][kk] = *(short8*)&o;
        }
    }

    // ---- stage ALL 256 B rows: 16 rows/thread, 8 f32 granule each ----------
    // 16 lanes per row (s0 = granule); sumsq butterfly over s0; swizzled write:
    // LDS image addr = (r*256 + s*16) ^ ((r&7)<<4)
    {
        const int s0 = tid & 15;
        const int rb = tid >> 4;             // 0..15
        #pragma unroll
        for (int b = 0; b < 16; b++) {
            const int r = rb + b * 16;
            const float* src = gBase + (size_t)r * 128 + s0 * 8;
            f32x4 x = *(const f32x4*)(src);
            f32x4 y = *(const f32x4*)(src + 4);
            float ss = x[0]*x[0] + x[1]*x[1] + x[2]*x[2] + x[3]*x[3]
                     + y[0]*y[0] + y[1]*y[1] + y[2]*y[2] + y[3]*y[3];
            ss += __shfl_xor(ss, 1);
            ss += __shfl_xor(ss, 2);
            ss += __shfl_xor(ss, 4);
            ss += __shfl_xor(ss, 8);
            float inv = 1.0f / sqrtf(ss);
            u32x4 o;
            o.x = pk(x[0], x[1], inv);
            o.y = pk(x[2], x[3], inv);
            o.z = pk(y[0], y[1], inv);
            o.w = pk(y[2], y[3], inv);
            *(u32x4*)(gtile + ((r * 256 + s0 * 16) ^ ((r & 7) << 4))) = o;
        }
    }

    __syncthreads();                         // the ONLY barrier

    // ---- compute: 16 q-subtiles x 4 kk x 4 pg = 256 MFMA, free-running -----
    f32x4 mx[4];
    #pragma unroll
    for (int pg = 0; pg < 4; pg++)
        #pragma unroll
        for (int i = 0; i < 4; i++) mx[pg][i] = -1e30f;

    #pragma unroll
    for (int qt = 0; qt < 16; qt++) {
        const int r = qt * 16 + l15;
        const int rowoff = r * 256;
        const int swz = (r & 7) << 4;
        short8 b0 = *(const short8*)(gtile + ((rowoff +   0 + lhi * 16) ^ swz));
        short8 b1 = *(const short8*)(gtile + ((rowoff +  64 + lhi * 16) ^ swz));
        short8 b2 = *(const short8*)(gtile + ((rowoff + 128 + lhi * 16) ^ swz));
        short8 b3 = *(const short8*)(gtile + ((rowoff + 192 + lhi * 16) ^ swz));
        f32x4 acc[4];
        #pragma unroll
        for (int pg = 0; pg < 4; pg++) {
            #pragma unroll
            for (int i = 0; i < 4; i++) acc[pg][i] = 0.f;
            acc[pg] = __builtin_amdgcn_mfma_f32_16x16x32_bf16(a[pg][0], b0, acc[pg], 0, 0, 0);
            acc[pg] = __builtin_amdgcn_mfma_f32_16x16x32_bf16(a[pg][1], b1, acc[pg], 0, 0, 0);
            acc[pg] = __builtin_amdgcn_mfma_f32_16x16x32_bf16(a[pg][2], b2, acc[pg], 0, 0, 0);
            acc[pg] = __builtin_amdgcn_mfma_f32_16x16x32_bf16(a[pg][3], b3, acc[pg], 0, 0, 0);
        }
        #pragma unroll
        for (int pg = 0; pg < 4; pg++)
            #pragma unroll
            for (int i = 0; i < 4; i++) mx[pg][i] = fmaxf(mx[pg][i], acc[pg][i]);
    }

    // reduce max over the 16 q-columns (C/D col = lane&15)
    #pragma unroll
    for (int pg = 0; pg < 4; pg++)
        #pragma unroll
        for (int i = 0; i < 4; i++) {
            float v = mx[pg][i];
            v = fmaxf(v, __shfl_xor(v, 1));
            v = fmaxf(v, __shfl_xor(v, 2));
            v = fmaxf(v, __shfl_xor(v, 4));
            v = fmaxf(v, __shfl_xor(v, 8));
            mx[pg][i] = v;
        }
    if (l15 == 0) {
        #pragma unroll
        for (int pg = 0; pg < 4; pg++)
            #pragma unroll
            for (int i = 0; i < 4; i++) {
                int row = rowbase + pg * 16 + lhi * 4 + i;   // [0,4096)
                int n = row >> 10, p = row & 1023;
                sp_part[((size_t)(n * 8 + m) * 4 + qq) * 1024 + p] = mx[pg][i];
            }
    }
}

// --------- Kernel 2: fused fold + scores + bilinear upsample ---------------
// grid (65, 4): bx<64 -> 8-row output band; bx==64 -> scores[n]
__global__ __launch_bounds__(256) void kfinal(const float* __restrict__ sp_part,
                                              const float* __restrict__ mask,
                                              float* __restrict__ out) {
    const int n = blockIdx.y;
    const int bx = blockIdx.x;
    const int t = threadIdx.x;
    float* pix = out + 4;

    if (bx == 64) {  // ---- scores[n] = mean_m max_p dist ----
        __shared__ float smax[4];
        float acc = 0.f;
        for (int m = 0; m < 8; m++) {
            const float* base = sp_part + (size_t)(n * 8 + m) * 4 * 1024;
            float lm = -1e30f;
            #pragma unroll
            for (int i = 0; i < 4; i++) {
                int p = i * 256 + t;
                float dot = fmaxf(fmaxf(base[p], base[1024 + p]),
                                  fmaxf(base[2048 + p], base[3072 + p]));
                float d = sqrtf(fmaxf(2.0f - 2.0f * dot, 0.0f)) * 0.5f * mask[n * 1024 + p];
                lm = fmaxf(lm, d);
            }
            #pragma unroll
            for (int d = 32; d; d >>= 1) lm = fmaxf(lm, __shfl_xor(lm, d));
            if ((t & 63) == 0) smax[t >> 6] = lm;
            __syncthreads();
            if (t == 0) acc += fmaxf(fmaxf(smax[0], smax[1]), fmaxf(smax[2], smax[3]));
            __syncthreads();
        }
        if (t == 0) out[n] = acc * 0.125f;
        return;
    }

    // ---- output band: rows [bx*8, bx*8+8); needs 2 consecutive patch rows ----
    __shared__ float sp_row[2][32];
    const int band = bx * 8;
    const int pr_lo = (int)floorf((band + 0.5f) * 0.0625f - 0.5f);
    const int row0 = min(max(pr_lo, 0), 31);
    const int row1 = min(max(pr_lo + 1, 0), 31);
    {
        int v = t >> 2, sub = t & 3;          // 64 values x 4 threads
        int vr = v >> 5, vc = v & 31;
        int p = (vr ? row1 : row0) * 32 + vc;
        float sum = 0.f;
        #pragma unroll
        for (int mi = 0; mi < 2; mi++) {
            int m = sub * 2 + mi;
            const float* base = sp_part + (size_t)(n * 8 + m) * 4 * 1024 + p;
            float dot = fmaxf(fmaxf(base[0], base[1024]),
                              fmaxf(base[2048], base[3072]));
            sum += sqrtf(fmaxf(2.0f - 2.0f * dot, 0.0f)) * 0.5f;
        }
        sum *= mask[n * 1024 + p];
        sum += __shfl_xor(sum, 1);
        sum += __shfl_xor(sum, 2);
        if (sub == 0) sp_row[vr][vc] = sum * 0.125f;
    }
    __syncthreads();
    #pragma unroll
    for (int i = 0; i < 16; i++) {
        int idx = i * 256 + t;
        int yl = idx >> 9, x = idx & 511;
        int y = band + yl;
        float fy = (y + 0.5f) * 0.0625f - 0.5f;
        float ty = fy - (float)pr_lo;          // rows {pr_lo, pr_lo+1}; clamped dup at edges
        float fx = (x + 0.5f) * 0.0625f - 0.5f;
        float xf = floorf(fx);
        float tx = fx - xf;
        int x0 = (int)xf;
        int x0c = min(max(x0, 0), 31), x1c = min(max(x0 + 1, 0), 31);
        float v00 = sp_row[0][x0c], v01 = sp_row[0][x1c];
        float v10 = sp_row[1][x0c], v11 = sp_row[1][x1c];
        float v0 = v00 + tx * (v01 - v00);
        float v1 = v10 + tx * (v11 - v10);
        pix[(size_t)n * 262144 + (size_t)y * 512 + x] = v0 + ty * (v1 - v0);
    }
}

extern "C" void kernel_launch(void* const* d_in, const int* in_sizes, int n_in,
                              void* d_out, int out_size, void* d_ws, size_t ws_size,
                              hipStream_t stream) {
    const float* feats = (const float*)d_in[0];           // [4,1024,128] f32
    const float* nfeats = (const float*)d_in[1];          // [8,1024,128] f32
    const float* mask = (const float*)d_in[2];            // [4,1024] f32
    float* out = (float*)d_out;                           // [4] scores + [4,512,512]

    float* sp_part = (float*)d_ws;                        // 512 KB only

    kscore<<<dim3(8, 64), 256, 0, stream>>>(feats, nfeats, sp_part);
    kfinal<<<dim3(65, 4), 256, 0, stream>>>(sp_part, mask, out);
}